// Round 4
// baseline (137.124 us; speedup 1.0000x reference)
//
#include <hip/hip_runtime.h>

#define DEVINL __device__ __forceinline__

constexpr int E    = 768;
constexpr int TSEQ = 512;
constexpr int NH   = 12;
constexpr int HD   = 64;
constexpr float RSCALE = 0.036084391824351615f; // 1/sqrt(768)

typedef short bf16x8 __attribute__((ext_vector_type(8)));
typedef float floatx4 __attribute__((ext_vector_type(4)));

DEVINL short f2bf(float x) {
    union { float f; unsigned u; } v; v.f = x;
    unsigned r = v.u + 0x7FFFu + ((v.u >> 16) & 1u);
    return (short)(r >> 16);
}
DEVINL float bf2f(short s) {
    union { unsigned u; float f; } v;
    v.u = ((unsigned)(unsigned short)s) << 16;
    return v.f;
}

// ---------------------------------------------------------------------------
// Kernel 1: QKV projections via MFMA with INLINE fp32->bf16 conversion
// (replaces the old separate convert kernel) and register-prefetched
// staging (next K-tile's global loads issue while current tile computes).
// Block = 64x64 output tile (one head wide), 4 waves.
// LDS rows padded to 72 bf16 -> conflict-free b128 reads/writes.
// ---------------------------------------------------------------------------
__global__ __launch_bounds__(256) void qkv_mfma(
    const float* __restrict__ x,
    const float* __restrict__ wq, const float* __restrict__ bq,
    const float* __restrict__ wk, const float* __restrict__ bk,
    const float* __restrict__ wv, const float* __restrict__ bv,
    short* __restrict__ Qo, short* __restrict__ Ko, short* __restrict__ Vo)
{
    const float* W; const float* bias; short* outp;
    if (blockIdx.z == 0)      { W = wq; bias = bq; outp = Qo; }
    else if (blockIdx.z == 1) { W = wk; bias = bk; outp = Ko; }
    else                      { W = wv; bias = bv; outp = Vo; }

    __shared__ short As[64 * 72];
    __shared__ short Bs[64 * 72];

    const int m0   = blockIdx.x * 64;
    const int n0   = blockIdx.y * 64;    // == head * 64
    const int tid  = threadIdx.x;
    const int wvi  = tid >> 6;
    const int lane = tid & 63;
    const int col  = lane & 15;
    const int quad = lane >> 4;

    const int r0 = tid >> 3, kc0 = tid & 7;
    const int r1 = r0 + 32;

    floatx4 acc[4];
    #pragma unroll
    for (int i = 0; i < 4; i++) acc[i] = (floatx4){0.f, 0.f, 0.f, 0.f};

    // staging registers: [buf][a0lo,a0hi,a1lo,a1hi,b0lo,b0hi,b1lo,b1hi]
    float4 st[2][8];

    #define QKV_LOAD(buf, kk) do { \
        st[buf][0] = *(const float4*)&x[(size_t)(m0 + r0) * E + (kk) + kc0*8]; \
        st[buf][1] = *(const float4*)&x[(size_t)(m0 + r0) * E + (kk) + kc0*8 + 4]; \
        st[buf][2] = *(const float4*)&x[(size_t)(m0 + r1) * E + (kk) + kc0*8]; \
        st[buf][3] = *(const float4*)&x[(size_t)(m0 + r1) * E + (kk) + kc0*8 + 4]; \
        st[buf][4] = *(const float4*)&W[(size_t)(n0 + r0) * E + (kk) + kc0*8]; \
        st[buf][5] = *(const float4*)&W[(size_t)(n0 + r0) * E + (kk) + kc0*8 + 4]; \
        st[buf][6] = *(const float4*)&W[(size_t)(n0 + r1) * E + (kk) + kc0*8]; \
        st[buf][7] = *(const float4*)&W[(size_t)(n0 + r1) * E + (kk) + kc0*8 + 4]; \
    } while (0)

    #define QKV_STORE(dst, lo, hi) do { \
        bf16x8 o_; \
        o_[0] = f2bf((lo).x); o_[1] = f2bf((lo).y); o_[2] = f2bf((lo).z); o_[3] = f2bf((lo).w); \
        o_[4] = f2bf((hi).x); o_[5] = f2bf((hi).y); o_[6] = f2bf((hi).z); o_[7] = f2bf((hi).w); \
        *(bf16x8*)(dst) = o_; \
    } while (0)

    #define QKV_STAGE(buf) do { \
        QKV_STORE(&As[r0*72 + kc0*8], st[buf][0], st[buf][1]); \
        QKV_STORE(&As[r1*72 + kc0*8], st[buf][2], st[buf][3]); \
        QKV_STORE(&Bs[r0*72 + kc0*8], st[buf][4], st[buf][5]); \
        QKV_STORE(&Bs[r1*72 + kc0*8], st[buf][6], st[buf][7]); \
    } while (0)

    #define QKV_COMPUTE() do { \
        _Pragma("unroll") \
        for (int k32 = 0; k32 < 2; ++k32) { \
            bf16x8 bfr = *(const bf16x8*)&Bs[(wvi*16 + col)*72 + k32*32 + quad*8]; \
            _Pragma("unroll") \
            for (int ms = 0; ms < 4; ++ms) { \
                bf16x8 afr = *(const bf16x8*)&As[(ms*16 + col)*72 + k32*32 + quad*8]; \
                acc[ms] = __builtin_amdgcn_mfma_f32_16x16x32_bf16(afr, bfr, acc[ms], 0, 0, 0); \
            } \
        } \
    } while (0)

    QKV_LOAD(0, 0);
    #pragma unroll 1
    for (int it2 = 0; it2 < 6; ++it2) {
        const int k0 = it2 * 128;
        __syncthreads();
        QKV_STAGE(0);
        QKV_LOAD(1, k0 + 64);          // prefetch next tile during compute
        __syncthreads();
        QKV_COMPUTE();
        __syncthreads();
        QKV_STAGE(1);
        if (it2 < 5) QKV_LOAD(0, k0 + 128);
        __syncthreads();
        QKV_COMPUTE();
    }
    #undef QKV_LOAD
    #undef QKV_STORE
    #undef QKV_STAGE
    #undef QKV_COMPUTE

    // epilogue: C layout row = quad*4+r, col = lane&15 (n within wave slice)
    const float bn = bias[n0 + wvi*16 + col];
    const int h = blockIdx.y;
    #pragma unroll
    for (int ms = 0; ms < 4; ms++) {
        #pragma unroll
        for (int r = 0; r < 4; r++) {
            int m = m0 + ms*16 + quad*4 + r;
            int bb = m >> 9, l = m & 511;
            outp[(((size_t)(bb*NH + h)) * TSEQ + l) * HD + wvi*16 + col] =
                f2bf(acc[ms][r] + bn);
        }
    }
}

// ---------------------------------------------------------------------------
// Kernel 2: Kp[b][h][o][t][d] = (1/scale) * sum_i w1[(h*8+o)*12+i] * K[b][i][t][d]
// One thread computes ALL 8 'o' outputs for its (t, d8) chunk, so the 12
// K-chunk loads are done once instead of 8x (151 MB -> 19 MB reads).
// ---------------------------------------------------------------------------
__global__ __launch_bounds__(256) void kmix_kernel(
    const short* __restrict__ K,   // [B,12,T,64] bf16
    const float* __restrict__ w1,  // [96,12] fp32
    short* __restrict__ Kp)        // [B,12,8,T,64] bf16
{
    const int g  = blockIdx.x * 256 + threadIdx.x;   // 98304 threads
    const int d8 = g & 7;
    const int t  = (g >> 3) & 511;
    const int bh = g >> 12;          // b*12 + h (uniform per block)
    const int h  = bh % NH;
    const int b  = bh / NH;

    float kv[12][8];
    #pragma unroll
    for (int i = 0; i < 12; ++i) {
        bf16x8 raw = *(const bf16x8*)&K[(((size_t)(b*NH + i)) * TSEQ + t) * HD + d8*8];
        #pragma unroll
        for (int j = 0; j < 8; ++j) kv[i][j] = bf2f(raw[j]);
    }

    short* outbase = Kp + (((size_t)bh * 8) * TSEQ + t) * HD + d8*8;
    #pragma unroll
    for (int o = 0; o < 8; ++o) {
        float acc[8] = {};
        #pragma unroll
        for (int i = 0; i < 12; ++i) {
            const float w = w1[(h*8 + o)*12 + i] * RSCALE;
            #pragma unroll
            for (int j = 0; j < 8; ++j) acc[j] = fmaf(w, kv[i][j], acc[j]);
        }
        bf16x8 ov;
        #pragma unroll
        for (int j = 0; j < 8; ++j) ov[j] = f2bf(acc[j]);
        *(bf16x8*)&outbase[(size_t)o * TSEQ * HD] = ov;
    }
}

// group-of-8 padded row offset (conflict-free transpose writes + aligned b128 reads)
DEVINL int vrow(int r) { return r*40 + (r >> 3)*8; }

// ---------------------------------------------------------------------------
// Kernel 3: MFMA attention. Block = (b, h, l-tile 64, t-quarter 128).
// (a) register-prefetch of next 32-t K/V tile issued right after LDS staging
// (latency hides under accS+MLP); (b) accS split into two o-halves (32 VGPR
// freed); (c) s_setprio around MFMA clusters. FP order identical to baseline.
// ---------------------------------------------------------------------------
__global__ __launch_bounds__(256, 3) void attn_mfma(
    const short* __restrict__ Qg,   // [B,12,T,64] bf16
    const short* __restrict__ Kg,   // [B,12,8,T,64] bf16
    const short* __restrict__ Vg,   // [B,12,T,64] bf16
    const float* __restrict__ b1, const float* __restrict__ w2,
    const float* __restrict__ b2, const float* __restrict__ w3,
    const float* __restrict__ b3, const float* __restrict__ w4,
    const float* __restrict__ b4,
    float* __restrict__ Pout)       // [768][64][64] fp32 partials
{
    __shared__ short Ks[256 * 72];   // [o*32+t][72]  (64d used)
    __shared__ short Vt[2624];       // transposed V: [d][t], group-padded
    __shared__ short As[2624];       // A weights:    [l][t], group-padded

    const int blk = blockIdx.x;          // ((b*12+h)*8+lt)*4 + qtr
    const int qtr = blk & 3;
    const int lt  = (blk >> 2) & 7;
    const int bh  = blk >> 5;
    const int h   = bh % NH;
    const int l0  = lt * 64;
    const int tb  = qtr * 128;

    const int tid  = threadIdx.x;
    const int wv   = tid >> 6;
    const int lane = tid & 63;
    const int col  = lane & 15;
    const int quad = lane >> 4;
    const int wl   = wv >> 1;   // l-half for S'
    const int wt   = wv & 1;    // t-half for S'

    float b1r[8], w2r[8], w3r[4], b3r[4], w4r[4];
    #pragma unroll
    for (int o = 0; o < 8; o++) { b1r[o] = b1[h*8+o]; w2r[o] = w2[h*8+o]; }
    #pragma unroll
    for (int j = 0; j < 4; j++) { w3r[j] = w3[h*4+j]; b3r[j] = b3[h*4+j]; w4r[j] = w4[h*4+j]; }
    const float b2r = b2[h];
    const float b4r = b4[h];

    bf16x8 qa[2][2];
    {
        const short* qb = Qg + ((size_t)bh * TSEQ + l0 + wl*32 + col) * HD;
        qa[0][0] = *(const bf16x8*)&qb[quad*8];
        qa[0][1] = *(const bf16x8*)&qb[32 + quad*8];
        qa[1][0] = *(const bf16x8*)&qb[16*HD + quad*8];
        qa[1][1] = *(const bf16x8*)&qb[16*HD + 32 + quad*8];
    }

    floatx4 accO[4];
    #pragma unroll
    for (int d16 = 0; d16 < 4; d16++) accO[d16] = (floatx4){0.f, 0.f, 0.f, 0.f};

    const short* kbase = Kg + (size_t)bh * 8 * TSEQ * HD;
    const short* vbase = Vg + (size_t)bh * TSEQ * HD;

    const int tl = tid >> 3;   // 0..31 staging row
    const int dc = tid & 7;    // staging 16B chunk

    bf16x8 kt[2][8];
    bf16x8 vt2[2];

    #define ATTN_LOAD(buf, t0) do { \
        _Pragma("unroll") \
        for (int o_ = 0; o_ < 8; ++o_) \
            kt[buf][o_] = *(const bf16x8*)&kbase[((size_t)o_ * TSEQ + (t0) + tl) * HD + dc*8]; \
        vt2[buf] = *(const bf16x8*)&vbase[(size_t)((t0) + tl) * HD + dc*8]; \
    } while (0)

    #define ATTN_STAGE(buf) do { \
        _Pragma("unroll") \
        for (int o_ = 0; o_ < 8; ++o_) \
            *(bf16x8*)&Ks[(o_*32 + tl)*72 + dc*8] = kt[buf][o_]; \
        _Pragma("unroll") \
        for (int j_ = 0; j_ < 8; ++j_) \
            Vt[vrow(dc*8 + j_) + tl] = vt2[buf][j_]; \
    } while (0)

    // accS in two o-halves; z2 accumulation order (o = 0..7) identical to the
    // baseline mlp_eval, so results are bitwise-unchanged.
    #define ATTN_COMPUTE() do { \
        float z2a[8]; \
        _Pragma("unroll") \
        for (int i_ = 0; i_ < 8; ++i_) z2a[i_] = b2r; \
        _Pragma("unroll") \
        for (int oh = 0; oh < 2; ++oh) { \
            floatx4 accS[4][2]; \
            _Pragma("unroll") \
            for (int o4 = 0; o4 < 4; ++o4) { \
                accS[o4][0] = (floatx4){0.f, 0.f, 0.f, 0.f}; \
                accS[o4][1] = (floatx4){0.f, 0.f, 0.f, 0.f}; \
            } \
            __builtin_amdgcn_s_setprio(1); \
            _Pragma("unroll") \
            for (int k32 = 0; k32 < 2; ++k32) { \
                _Pragma("unroll") \
                for (int o4 = 0; o4 < 4; ++o4) { \
                    const int o_ = oh*4 + o4; \
                    bf16x8 bfr = *(const bf16x8*)&Ks[(o_*32 + wt*16 + col)*72 + k32*32 + quad*8]; \
                    accS[o4][0] = __builtin_amdgcn_mfma_f32_16x16x32_bf16(qa[0][k32], bfr, accS[o4][0], 0, 0, 0); \
                    accS[o4][1] = __builtin_amdgcn_mfma_f32_16x16x32_bf16(qa[1][k32], bfr, accS[o4][1], 0, 0, 0); \
                } \
            } \
            __builtin_amdgcn_s_setprio(0); \
            _Pragma("unroll") \
            for (int li = 0; li < 2; ++li) { \
                _Pragma("unroll") \
                for (int r = 0; r < 4; ++r) { \
                    _Pragma("unroll") \
                    for (int o4 = 0; o4 < 4; ++o4) { \
                        float z1 = fmaxf(accS[o4][li][r] + b1r[oh*4+o4], 0.0f); \
                        z2a[li*4+r] = fmaf(z1, w2r[oh*4+o4], z2a[li*4+r]); \
                    } \
                } \
            } \
        } \
        _Pragma("unroll") \
        for (int li = 0; li < 2; ++li) { \
            _Pragma("unroll") \
            for (int r = 0; r < 4; ++r) { \
                float z2 = z2a[li*4+r]; \
                float a_ = b4r; \
                _Pragma("unroll") \
                for (int j_ = 0; j_ < 4; ++j_) { \
                    float z3 = fmaxf(fmaf(z2, w3r[j_], b3r[j_]), 0.0f); \
                    a_ = fmaf(z3, w4r[j_], a_); \
                } \
                As[vrow(wl*32 + li*16 + quad*4 + r) + wt*16 + col] = f2bf(a_); \
            } \
        } \
        __syncthreads(); \
        { \
            bf16x8 afr = *(const bf16x8*)&As[vrow(wv*16 + col) + quad*8]; \
            __builtin_amdgcn_s_setprio(1); \
            _Pragma("unroll") \
            for (int d16 = 0; d16 < 4; ++d16) { \
                bf16x8 vfr = *(const bf16x8*)&Vt[vrow(d16*16 + col) + quad*8]; \
                accO[d16] = __builtin_amdgcn_mfma_f32_16x16x32_bf16(afr, vfr, accO[d16], 0, 0, 0); \
            } \
            __builtin_amdgcn_s_setprio(0); \
        } \
    } while (0)

    ATTN_LOAD(0, tb);
    #pragma unroll 1
    for (int it2 = 0; it2 < 2; ++it2) {
        const int t0 = tb + it2 * 64;
        __syncthreads();
        ATTN_STAGE(0);
        ATTN_LOAD(1, t0 + 32);             // prefetch under accS+MLP+PV
        __syncthreads();
        ATTN_COMPUTE();
        __syncthreads();
        ATTN_STAGE(1);
        if (it2 == 0) ATTN_LOAD(0, t0 + 64);   // next iter's first tile
        __syncthreads();
        ATTN_COMPUTE();
    }
    #undef ATTN_LOAD
    #undef ATTN_STAGE
    #undef ATTN_COMPUTE

    float* pb = Pout + (size_t)blk * 64 * 64;
    #pragma unroll
    for (int d16 = 0; d16 < 4; d16++)
        #pragma unroll
        for (int r = 0; r < 4; r++)
            pb[(wv*16 + quad*4 + r) * 64 + d16*16 + col] = accO[d16][r];
}

// ---------------------------------------------------------------------------
// Kernel 4: sum 4 t-quarter partials, scatter to out[b][l][h*64+d].
// ---------------------------------------------------------------------------
__global__ __launch_bounds__(256) void reduce_kernel(
    const float* __restrict__ P, float* __restrict__ out)
{
    const int gi  = blockIdx.x * 256 + threadIdx.x;  // float4 units, 196608 total
    const int d4  = gi & 15;
    const int r   = (gi >> 4) & 63;
    const int grp = gi >> 10;            // (b*12+h)*8 + lt
    const int lt  = grp & 7;
    const int bh  = grp >> 3;
    const int h   = bh % NH;
    const int b   = bh / NH;

    const float* p0 = P + (size_t)grp * 4 * 4096 + r * 64 + d4 * 4;
    float4 s0 = *(const float4*)&p0[0];
    float4 s1 = *(const float4*)&p0[4096];
    float4 s2 = *(const float4*)&p0[8192];
    float4 s3 = *(const float4*)&p0[12288];
    float4 s;
    s.x = (s0.x + s1.x) + (s2.x + s3.x);
    s.y = (s0.y + s1.y) + (s2.y + s3.y);
    s.z = (s0.z + s1.z) + (s2.z + s3.z);
    s.w = (s0.w + s1.w) + (s2.w + s3.w);
    *(float4*)&out[((size_t)(b*TSEQ + lt*64 + r)) * E + h*64 + d4*4] = s;
}

// ---------------------------------------------------------------------------
extern "C" void kernel_launch(void* const* d_in, const int* in_sizes, int n_in,
                              void* d_out, int out_size, void* d_ws, size_t ws_size,
                              hipStream_t stream) {
    const float* x  = (const float*)d_in[0];
    const float* wq = (const float*)d_in[1];
    const float* bq = (const float*)d_in[2];
    const float* wk = (const float*)d_in[3];
    const float* bk = (const float*)d_in[4];
    const float* wv = (const float*)d_in[5];
    const float* bv = (const float*)d_in[6];
    const float* w1 = (const float*)d_in[7];
    const float* b1 = (const float*)d_in[8];
    const float* w2 = (const float*)d_in[9];
    const float* b2 = (const float*)d_in[10];
    const float* w3 = (const float*)d_in[11];
    const float* b3 = (const float*)d_in[12];
    const float* w4 = (const float*)d_in[13];
    const float* b4 = (const float*)d_in[14];
    float* out = (float*)d_out;

    short* Qb = (short*)d_ws;                       // 786432 bf16
    short* Kb = Qb + 786432;                        // 786432 bf16
    short* Vb = Kb + 786432;                        // 786432 bf16
    short* Kp = Vb + 786432;                        // 6291456 bf16
    float* P  = (float*)(Kp + 6291456);             // 3145728 fp32

    qkv_mfma<<<dim3(16, 12, 3), 256, 0, stream>>>(x, wq, bq, wk, bk, wv, bv, Qb, Kb, Vb);
    kmix_kernel<<<384, 256, 0, stream>>>(Kb, w1, Kp);
    attn_mfma<<<768, 256, 0, stream>>>(Qb, Kp, Vb, b1, w2, b2, w3, b3, w4, b4, P);
    reduce_kernel<<<768, 256, 0, stream>>>(P, out);
}

// Round 7
// 133.348 us; speedup vs baseline: 1.0283x; 1.0283x over previous
//
#include <hip/hip_runtime.h>

#define DEVINL __device__ __forceinline__

constexpr int E    = 768;
constexpr int TSEQ = 512;
constexpr int NH   = 12;
constexpr int HD   = 64;
constexpr float RSCALE = 0.036084391824351615f; // 1/sqrt(768)

typedef short bf16x8 __attribute__((ext_vector_type(8)));
typedef float floatx4 __attribute__((ext_vector_type(4)));

DEVINL short f2bf(float x) {
    union { float f; unsigned u; } v; v.f = x;
    unsigned r = v.u + 0x7FFFu + ((v.u >> 16) & 1u);
    return (short)(r >> 16);
}
DEVINL float bf2f(short s) {
    union { unsigned u; float f; } v;
    v.u = ((unsigned)(unsigned short)s) << 16;
    return v.f;
}

// ---------------------------------------------------------------------------
// Kernel 1: QKV projections via MFMA with INLINE fp32->bf16 conversion and
// register-prefetched staging. Block = 64x64 output tile, 4 waves.
// LDS rows padded to 72 bf16 -> conflict-free b128 reads/writes.
// ---------------------------------------------------------------------------
__global__ __launch_bounds__(256) void qkv_mfma(
    const float* __restrict__ x,
    const float* __restrict__ wq, const float* __restrict__ bq,
    const float* __restrict__ wk, const float* __restrict__ bk,
    const float* __restrict__ wv, const float* __restrict__ bv,
    short* __restrict__ Qo, short* __restrict__ Ko, short* __restrict__ Vo)
{
    const float* W; const float* bias; short* outp;
    if (blockIdx.z == 0)      { W = wq; bias = bq; outp = Qo; }
    else if (blockIdx.z == 1) { W = wk; bias = bk; outp = Ko; }
    else                      { W = wv; bias = bv; outp = Vo; }

    __shared__ short As[64 * 72];
    __shared__ short Bs[64 * 72];

    const int m0   = blockIdx.x * 64;
    const int n0   = blockIdx.y * 64;    // == head * 64
    const int tid  = threadIdx.x;
    const int wvi  = tid >> 6;
    const int lane = tid & 63;
    const int col  = lane & 15;
    const int quad = lane >> 4;

    const int r0 = tid >> 3, kc0 = tid & 7;
    const int r1 = r0 + 32;

    floatx4 acc[4];
    #pragma unroll
    for (int i = 0; i < 4; i++) acc[i] = (floatx4){0.f, 0.f, 0.f, 0.f};

    float4 st[2][8];

    #define QKV_LOAD(buf, kk) do { \
        st[buf][0] = *(const float4*)&x[(size_t)(m0 + r0) * E + (kk) + kc0*8]; \
        st[buf][1] = *(const float4*)&x[(size_t)(m0 + r0) * E + (kk) + kc0*8 + 4]; \
        st[buf][2] = *(const float4*)&x[(size_t)(m0 + r1) * E + (kk) + kc0*8]; \
        st[buf][3] = *(const float4*)&x[(size_t)(m0 + r1) * E + (kk) + kc0*8 + 4]; \
        st[buf][4] = *(const float4*)&W[(size_t)(n0 + r0) * E + (kk) + kc0*8]; \
        st[buf][5] = *(const float4*)&W[(size_t)(n0 + r0) * E + (kk) + kc0*8 + 4]; \
        st[buf][6] = *(const float4*)&W[(size_t)(n0 + r1) * E + (kk) + kc0*8]; \
        st[buf][7] = *(const float4*)&W[(size_t)(n0 + r1) * E + (kk) + kc0*8 + 4]; \
    } while (0)

    #define QKV_STORE(dst, lo, hi) do { \
        bf16x8 o_; \
        o_[0] = f2bf((lo).x); o_[1] = f2bf((lo).y); o_[2] = f2bf((lo).z); o_[3] = f2bf((lo).w); \
        o_[4] = f2bf((hi).x); o_[5] = f2bf((hi).y); o_[6] = f2bf((hi).z); o_[7] = f2bf((hi).w); \
        *(bf16x8*)(dst) = o_; \
    } while (0)

    #define QKV_STAGE(buf) do { \
        QKV_STORE(&As[r0*72 + kc0*8], st[buf][0], st[buf][1]); \
        QKV_STORE(&As[r1*72 + kc0*8], st[buf][2], st[buf][3]); \
        QKV_STORE(&Bs[r0*72 + kc0*8], st[buf][4], st[buf][5]); \
        QKV_STORE(&Bs[r1*72 + kc0*8], st[buf][6], st[buf][7]); \
    } while (0)

    #define QKV_COMPUTE() do { \
        _Pragma("unroll") \
        for (int k32 = 0; k32 < 2; ++k32) { \
            bf16x8 bfr = *(const bf16x8*)&Bs[(wvi*16 + col)*72 + k32*32 + quad*8]; \
            _Pragma("unroll") \
            for (int ms = 0; ms < 4; ++ms) { \
                bf16x8 afr = *(const bf16x8*)&As[(ms*16 + col)*72 + k32*32 + quad*8]; \
                acc[ms] = __builtin_amdgcn_mfma_f32_16x16x32_bf16(afr, bfr, acc[ms], 0, 0, 0); \
            } \
        } \
    } while (0)

    QKV_LOAD(0, 0);
    #pragma unroll 1
    for (int it2 = 0; it2 < 6; ++it2) {
        const int k0 = it2 * 128;
        __syncthreads();
        QKV_STAGE(0);
        QKV_LOAD(1, k0 + 64);          // prefetch next tile during compute
        __syncthreads();
        QKV_COMPUTE();
        __syncthreads();
        QKV_STAGE(1);
        if (it2 < 5) QKV_LOAD(0, k0 + 128);
        __syncthreads();
        QKV_COMPUTE();
    }
    #undef QKV_LOAD
    #undef QKV_STORE
    #undef QKV_STAGE
    #undef QKV_COMPUTE

    const float bn = bias[n0 + wvi*16 + col];
    const int h = blockIdx.y;
    #pragma unroll
    for (int ms = 0; ms < 4; ms++) {
        #pragma unroll
        for (int r = 0; r < 4; r++) {
            int m = m0 + ms*16 + quad*4 + r;
            int bb = m >> 9, l = m & 511;
            outp[(((size_t)(bb*NH + h)) * TSEQ + l) * HD + wvi*16 + col] =
                f2bf(acc[ms][r] + bn);
        }
    }
}

// ---------------------------------------------------------------------------
// Kernel 2: Kp[b][h][o][t][d] = (1/scale) * sum_i w1[(h*8+o)*12+i] * K[b][i][t][d]
// One thread computes ALL 8 'o' outputs for its (t, d8) chunk (8x read dedup).
// ---------------------------------------------------------------------------
__global__ __launch_bounds__(256) void kmix_kernel(
    const short* __restrict__ K,   // [B,12,T,64] bf16
    const float* __restrict__ w1,  // [96,12] fp32
    short* __restrict__ Kp)        // [B,12,8,T,64] bf16
{
    const int g  = blockIdx.x * 256 + threadIdx.x;   // 98304 threads
    const int d8 = g & 7;
    const int t  = (g >> 3) & 511;
    const int bh = g >> 12;          // b*12 + h (uniform per block)
    const int h  = bh % NH;
    const int b  = bh / NH;

    float kv[12][8];
    #pragma unroll
    for (int i = 0; i < 12; ++i) {
        bf16x8 raw = *(const bf16x8*)&K[(((size_t)(b*NH + i)) * TSEQ + t) * HD + d8*8];
        #pragma unroll
        for (int j = 0; j < 8; ++j) kv[i][j] = bf2f(raw[j]);
    }

    short* outbase = Kp + (((size_t)bh * 8) * TSEQ + t) * HD + d8*8;
    #pragma unroll
    for (int o = 0; o < 8; ++o) {
        float acc[8] = {};
        #pragma unroll
        for (int i = 0; i < 12; ++i) {
            const float w = w1[(h*8 + o)*12 + i] * RSCALE;
            #pragma unroll
            for (int j = 0; j < 8; ++j) acc[j] = fmaf(w, kv[i][j], acc[j]);
        }
        bf16x8 ov;
        #pragma unroll
        for (int j = 0; j < 8; ++j) ov[j] = f2bf(acc[j]);
        *(bf16x8*)&outbase[(size_t)o * TSEQ * HD] = ov;
    }
}

// group-of-8 padded row offset (conflict-free transpose writes + aligned b128 reads)
DEVINL int vrow(int r) { return r*40 + (r >> 3)*8; }

// ---------------------------------------------------------------------------
// Kernel 3: MFMA attention. Block = (b, h, l-tile 64, t-quarter 128).
// Single-buffered staging loop (no VGPR spill: ~130 live VGPR vs round-4's
// ~180 > 168 cap at waves/EU=3). No setprio (lockstep kernel, T5 n/a).
// accS o-halved (FP order identical to baseline mlp_eval).
// Epilogue: fp32 atomic fadd straight into out — reduce kernel + P buffer
// eliminated (harness zeroes out before launch).
// ---------------------------------------------------------------------------
__global__ __launch_bounds__(256, 3) void attn_mfma(
    const short* __restrict__ Qg,   // [B,12,T,64] bf16
    const short* __restrict__ Kg,   // [B,12,8,T,64] bf16
    const short* __restrict__ Vg,   // [B,12,T,64] bf16
    const float* __restrict__ b1, const float* __restrict__ w2,
    const float* __restrict__ b2, const float* __restrict__ w3,
    const float* __restrict__ b3, const float* __restrict__ w4,
    const float* __restrict__ b4,
    float* __restrict__ out)        // [B,T,768] fp32, pre-zeroed
{
    __shared__ short Ks[256 * 72];   // [o*32+t][72]  (64d used)
    __shared__ short Vt[2624];       // transposed V: [d][t], group-padded
    __shared__ short As[2624];       // A weights:    [l][t], group-padded

    const int blk = blockIdx.x;          // ((b*12+h)*8+lt)*4 + qtr
    const int qtr = blk & 3;
    const int lt  = (blk >> 2) & 7;
    const int bh  = blk >> 5;
    const int h   = bh % NH;
    const int b   = bh / NH;
    const int l0  = lt * 64;
    const int tb  = qtr * 128;

    const int tid  = threadIdx.x;
    const int wv   = tid >> 6;
    const int lane = tid & 63;
    const int col  = lane & 15;
    const int quad = lane >> 4;
    const int wl   = wv >> 1;   // l-half for S'
    const int wt   = wv & 1;    // t-half for S'

    float b1r[8], w2r[8], w3r[4], b3r[4], w4r[4];
    #pragma unroll
    for (int o = 0; o < 8; o++) { b1r[o] = b1[h*8+o]; w2r[o] = w2[h*8+o]; }
    #pragma unroll
    for (int j = 0; j < 4; j++) { w3r[j] = w3[h*4+j]; b3r[j] = b3[h*4+j]; w4r[j] = w4[h*4+j]; }
    const float b2r = b2[h];
    const float b4r = b4[h];

    bf16x8 qa[2][2];
    {
        const short* qb = Qg + ((size_t)bh * TSEQ + l0 + wl*32 + col) * HD;
        qa[0][0] = *(const bf16x8*)&qb[quad*8];
        qa[0][1] = *(const bf16x8*)&qb[32 + quad*8];
        qa[1][0] = *(const bf16x8*)&qb[16*HD + quad*8];
        qa[1][1] = *(const bf16x8*)&qb[16*HD + 32 + quad*8];
    }

    floatx4 accO[4];
    #pragma unroll
    for (int d16 = 0; d16 < 4; d16++) accO[d16] = (floatx4){0.f, 0.f, 0.f, 0.f};

    const short* kbase = Kg + (size_t)bh * 8 * TSEQ * HD;
    const short* vbase = Vg + (size_t)bh * TSEQ * HD;

    const int tl = tid >> 3;   // 0..31 staging row
    const int dc = tid & 7;    // staging 16B chunk

    #pragma unroll 1
    for (int it = 0; it < 4; it++) {
        const int t0 = tb + it * 32;

        // loads issue here, overlapping the tail of the previous compute
        bf16x8 ktmp[8];
        #pragma unroll
        for (int o = 0; o < 8; o++)
            ktmp[o] = *(const bf16x8*)&kbase[((size_t)o * TSEQ + t0 + tl) * HD + dc*8];
        bf16x8 vtmp = *(const bf16x8*)&vbase[(size_t)(t0 + tl) * HD + dc*8];

        __syncthreads();

        #pragma unroll
        for (int o = 0; o < 8; o++)
            *(bf16x8*)&Ks[(o*32 + tl)*72 + dc*8] = ktmp[o];
        #pragma unroll
        for (int j = 0; j < 8; j++)
            Vt[vrow(dc*8 + j) + tl] = vtmp[j];   // transpose: Vt[d][t]

        __syncthreads();

        // --- S' (QK'^T) + talking-heads MLP, o-halved accS ---
        float z2a[8];
        #pragma unroll
        for (int i_ = 0; i_ < 8; ++i_) z2a[i_] = b2r;

        #pragma unroll
        for (int oh = 0; oh < 2; ++oh) {
            floatx4 accS[4][2];
            #pragma unroll
            for (int o4 = 0; o4 < 4; ++o4) {
                accS[o4][0] = (floatx4){0.f, 0.f, 0.f, 0.f};
                accS[o4][1] = (floatx4){0.f, 0.f, 0.f, 0.f};
            }
            #pragma unroll
            for (int k32 = 0; k32 < 2; ++k32) {
                #pragma unroll
                for (int o4 = 0; o4 < 4; ++o4) {
                    const int o_ = oh*4 + o4;
                    bf16x8 bfr = *(const bf16x8*)&Ks[(o_*32 + wt*16 + col)*72 + k32*32 + quad*8];
                    accS[o4][0] = __builtin_amdgcn_mfma_f32_16x16x32_bf16(qa[0][k32], bfr, accS[o4][0], 0, 0, 0);
                    accS[o4][1] = __builtin_amdgcn_mfma_f32_16x16x32_bf16(qa[1][k32], bfr, accS[o4][1], 0, 0, 0);
                }
            }
            #pragma unroll
            for (int li = 0; li < 2; ++li) {
                #pragma unroll
                for (int r = 0; r < 4; ++r) {
                    #pragma unroll
                    for (int o4 = 0; o4 < 4; ++o4) {
                        float z1 = fmaxf(accS[o4][li][r] + b1r[oh*4+o4], 0.0f);
                        z2a[li*4+r] = fmaf(z1, w2r[oh*4+o4], z2a[li*4+r]);
                    }
                }
            }
        }
        #pragma unroll
        for (int li = 0; li < 2; ++li) {
            #pragma unroll
            for (int r = 0; r < 4; ++r) {
                float z2 = z2a[li*4+r];
                float a_ = b4r;
                #pragma unroll
                for (int j_ = 0; j_ < 4; ++j_) {
                    float z3 = fmaxf(fmaf(z2, w3r[j_], b3r[j_]), 0.0f);
                    a_ = fmaf(z3, w4r[j_], a_);
                }
                As[vrow(wl*32 + li*16 + quad*4 + r) + wt*16 + col] = f2bf(a_);
            }
        }
        __syncthreads();

        // --- PV ---
        bf16x8 afr = *(const bf16x8*)&As[vrow(wv*16 + col) + quad*8];
        #pragma unroll
        for (int d16 = 0; d16 < 4; ++d16) {
            bf16x8 vfr = *(const bf16x8*)&Vt[vrow(d16*16 + col) + quad*8];
            accO[d16] = __builtin_amdgcn_mfma_f32_16x16x32_bf16(afr, vfr, accO[d16], 0, 0, 0);
        }
    }

    // epilogue: hw fp32 fadd into out (4 t-quarter blocks accumulate)
    float* ob = out + ((size_t)(b*TSEQ + l0)) * E + h*64;
    #pragma unroll
    for (int d16 = 0; d16 < 4; d16++)
        #pragma unroll
        for (int r = 0; r < 4; r++)
            unsafeAtomicAdd(&ob[(size_t)(wv*16 + quad*4 + r) * E + d16*16 + col],
                            accO[d16][r]);
}

// ---------------------------------------------------------------------------
extern "C" void kernel_launch(void* const* d_in, const int* in_sizes, int n_in,
                              void* d_out, int out_size, void* d_ws, size_t ws_size,
                              hipStream_t stream) {
    const float* x  = (const float*)d_in[0];
    const float* wq = (const float*)d_in[1];
    const float* bq = (const float*)d_in[2];
    const float* wk = (const float*)d_in[3];
    const float* bk = (const float*)d_in[4];
    const float* wv = (const float*)d_in[5];
    const float* bv = (const float*)d_in[6];
    const float* w1 = (const float*)d_in[7];
    const float* b1 = (const float*)d_in[8];
    const float* w2 = (const float*)d_in[9];
    const float* b2 = (const float*)d_in[10];
    const float* w3 = (const float*)d_in[11];
    const float* b3 = (const float*)d_in[12];
    const float* w4 = (const float*)d_in[13];
    const float* b4 = (const float*)d_in[14];
    float* out = (float*)d_out;

    short* Qb = (short*)d_ws;                       // 786432 bf16
    short* Kb = Qb + 786432;                        // 786432 bf16
    short* Vb = Kb + 786432;                        // 786432 bf16
    short* Kp = Vb + 786432;                        // 6291456 bf16

    qkv_mfma<<<dim3(16, 12, 3), 256, 0, stream>>>(x, wq, bq, wk, bk, wv, bv, Qb, Kb, Vb);
    kmix_kernel<<<384, 256, 0, stream>>>(Kb, w1, Kp);
    attn_mfma<<<768, 256, 0, stream>>>(Qb, Kp, Vb, b1, w2, b2, w3, b3, w4, b4, out);
}

// Round 8
// 133.103 us; speedup vs baseline: 1.0302x; 1.0018x over previous
//
#include <hip/hip_runtime.h>

#define DEVINL __device__ __forceinline__

constexpr int E    = 768;
constexpr int TSEQ = 512;
constexpr int NH   = 12;
constexpr int HD   = 64;
constexpr float RSCALE = 0.036084391824351615f; // 1/sqrt(768)

typedef short bf16x8 __attribute__((ext_vector_type(8)));
typedef float floatx4 __attribute__((ext_vector_type(4)));
typedef float floatx2 __attribute__((ext_vector_type(2)));

DEVINL short f2bf(float x) {
    union { float f; unsigned u; } v; v.f = x;
    unsigned r = v.u + 0x7FFFu + ((v.u >> 16) & 1u);
    return (short)(r >> 16);
}
DEVINL float bf2f(short s) {
    union { unsigned u; float f; } v;
    v.u = ((unsigned)(unsigned short)s) << 16;
    return v.f;
}

// ---------------------------------------------------------------------------
// Kernel 1: QKV projections via MFMA with INLINE fp32->bf16 conversion and
// register-prefetched staging. Block = 64x64 output tile, 4 waves.
// LDS rows padded to 72 bf16 -> conflict-free b128 reads/writes.
// (unchanged from R7)
// ---------------------------------------------------------------------------
__global__ __launch_bounds__(256) void qkv_mfma(
    const float* __restrict__ x,
    const float* __restrict__ wq, const float* __restrict__ bq,
    const float* __restrict__ wk, const float* __restrict__ bk,
    const float* __restrict__ wv, const float* __restrict__ bv,
    short* __restrict__ Qo, short* __restrict__ Ko, short* __restrict__ Vo)
{
    const float* W; const float* bias; short* outp;
    if (blockIdx.z == 0)      { W = wq; bias = bq; outp = Qo; }
    else if (blockIdx.z == 1) { W = wk; bias = bk; outp = Ko; }
    else                      { W = wv; bias = bv; outp = Vo; }

    __shared__ short As[64 * 72];
    __shared__ short Bs[64 * 72];

    const int m0   = blockIdx.x * 64;
    const int n0   = blockIdx.y * 64;    // == head * 64
    const int tid  = threadIdx.x;
    const int wvi  = tid >> 6;
    const int lane = tid & 63;
    const int col  = lane & 15;
    const int quad = lane >> 4;

    const int r0 = tid >> 3, kc0 = tid & 7;
    const int r1 = r0 + 32;

    floatx4 acc[4];
    #pragma unroll
    for (int i = 0; i < 4; i++) acc[i] = (floatx4){0.f, 0.f, 0.f, 0.f};

    float4 st[2][8];

    #define QKV_LOAD(buf, kk) do { \
        st[buf][0] = *(const float4*)&x[(size_t)(m0 + r0) * E + (kk) + kc0*8]; \
        st[buf][1] = *(const float4*)&x[(size_t)(m0 + r0) * E + (kk) + kc0*8 + 4]; \
        st[buf][2] = *(const float4*)&x[(size_t)(m0 + r1) * E + (kk) + kc0*8]; \
        st[buf][3] = *(const float4*)&x[(size_t)(m0 + r1) * E + (kk) + kc0*8 + 4]; \
        st[buf][4] = *(const float4*)&W[(size_t)(n0 + r0) * E + (kk) + kc0*8]; \
        st[buf][5] = *(const float4*)&W[(size_t)(n0 + r0) * E + (kk) + kc0*8 + 4]; \
        st[buf][6] = *(const float4*)&W[(size_t)(n0 + r1) * E + (kk) + kc0*8]; \
        st[buf][7] = *(const float4*)&W[(size_t)(n0 + r1) * E + (kk) + kc0*8 + 4]; \
    } while (0)

    #define QKV_STORE(dst, lo, hi) do { \
        bf16x8 o_; \
        o_[0] = f2bf((lo).x); o_[1] = f2bf((lo).y); o_[2] = f2bf((lo).z); o_[3] = f2bf((lo).w); \
        o_[4] = f2bf((hi).x); o_[5] = f2bf((hi).y); o_[6] = f2bf((hi).z); o_[7] = f2bf((hi).w); \
        *(bf16x8*)(dst) = o_; \
    } while (0)

    #define QKV_STAGE(buf) do { \
        QKV_STORE(&As[r0*72 + kc0*8], st[buf][0], st[buf][1]); \
        QKV_STORE(&As[r1*72 + kc0*8], st[buf][2], st[buf][3]); \
        QKV_STORE(&Bs[r0*72 + kc0*8], st[buf][4], st[buf][5]); \
        QKV_STORE(&Bs[r1*72 + kc0*8], st[buf][6], st[buf][7]); \
    } while (0)

    #define QKV_COMPUTE() do { \
        _Pragma("unroll") \
        for (int k32 = 0; k32 < 2; ++k32) { \
            bf16x8 bfr = *(const bf16x8*)&Bs[(wvi*16 + col)*72 + k32*32 + quad*8]; \
            _Pragma("unroll") \
            for (int ms = 0; ms < 4; ++ms) { \
                bf16x8 afr = *(const bf16x8*)&As[(ms*16 + col)*72 + k32*32 + quad*8]; \
                acc[ms] = __builtin_amdgcn_mfma_f32_16x16x32_bf16(afr, bfr, acc[ms], 0, 0, 0); \
            } \
        } \
    } while (0)

    QKV_LOAD(0, 0);
    #pragma unroll 1
    for (int it2 = 0; it2 < 6; ++it2) {
        const int k0 = it2 * 128;
        __syncthreads();
        QKV_STAGE(0);
        QKV_LOAD(1, k0 + 64);          // prefetch next tile during compute
        __syncthreads();
        QKV_COMPUTE();
        __syncthreads();
        QKV_STAGE(1);
        if (it2 < 5) QKV_LOAD(0, k0 + 128);
        __syncthreads();
        QKV_COMPUTE();
    }
    #undef QKV_LOAD
    #undef QKV_STORE
    #undef QKV_STAGE
    #undef QKV_COMPUTE

    const float bn = bias[n0 + wvi*16 + col];
    const int h = blockIdx.y;
    #pragma unroll
    for (int ms = 0; ms < 4; ms++) {
        #pragma unroll
        for (int r = 0; r < 4; r++) {
            int m = m0 + ms*16 + quad*4 + r;
            int bb = m >> 9, l = m & 511;
            outp[(((size_t)(bb*NH + h)) * TSEQ + l) * HD + wvi*16 + col] =
                f2bf(acc[ms][r] + bn);
        }
    }
}

// ---------------------------------------------------------------------------
// Kernel 2: Kp[b][h][o][t][d] = (1/scale) * sum_i w1[(h*8+o)*12+i] * K[b][i][t][d]
// CHANGED: 4 'o' outputs per thread (was 8) -> 768 blocks / 3 waves per SIMD
// (was 384 / 1.5) for latency hiding, still 4x read dedup. Per-element FP
// chain identical -> bitwise-same Kp.
// ---------------------------------------------------------------------------
__global__ __launch_bounds__(256) void kmix_kernel(
    const short* __restrict__ K,   // [B,12,T,64] bf16
    const float* __restrict__ w1,  // [96,12] fp32
    short* __restrict__ Kp)        // [B,12,8,T,64] bf16
{
    const int g  = blockIdx.x * 256 + threadIdx.x;   // 196608 threads
    const int d8 = g & 7;
    const int t  = (g >> 3) & 511;
    const int o2 = (g >> 12) & 1;    // which group of 4 'o'
    const int bh = g >> 13;          // b*12 + h
    const int h  = bh % NH;
    const int b  = bh / NH;

    float kv[12][8];
    #pragma unroll
    for (int i = 0; i < 12; ++i) {
        bf16x8 raw = *(const bf16x8*)&K[(((size_t)(b*NH + i)) * TSEQ + t) * HD + d8*8];
        #pragma unroll
        for (int j = 0; j < 8; ++j) kv[i][j] = bf2f(raw[j]);
    }

    short* outbase = Kp + (((size_t)bh * 8) * TSEQ + t) * HD + d8*8;
    #pragma unroll
    for (int oo = 0; oo < 4; ++oo) {
        const int o = o2*4 + oo;
        float acc[8] = {};
        #pragma unroll
        for (int i = 0; i < 12; ++i) {
            const float w = w1[(h*8 + o)*12 + i] * RSCALE;
            #pragma unroll
            for (int j = 0; j < 8; ++j) acc[j] = fmaf(w, kv[i][j], acc[j]);
        }
        bf16x8 ov;
        #pragma unroll
        for (int j = 0; j < 8; ++j) ov[j] = f2bf(acc[j]);
        *(bf16x8*)&outbase[(size_t)o * TSEQ * HD] = ov;
    }
}

// group-of-8 padded row offset (conflict-free transpose writes + aligned b128 reads)
DEVINL int vrow(int r) { return r*40 + (r >> 3)*8; }

// ---------------------------------------------------------------------------
// Kernel 3: MFMA attention. Block = (b, h, l-tile 64, t-quarter 128).
// Single-buffered staging (R7, no spill). CHANGED: talking-heads MLP on
// packed float2 (v_pk_fma_f32 / v_pk_max_f32) -> ~half the VALU ops.
// Exact fma per element, same accumulation order -> bitwise-identical.
// Epilogue: fp32 atomic fadd into pre-zeroed out (reduce fused, R7).
// ---------------------------------------------------------------------------
__global__ __launch_bounds__(256, 3) void attn_mfma(
    const short* __restrict__ Qg,   // [B,12,T,64] bf16
    const short* __restrict__ Kg,   // [B,12,8,T,64] bf16
    const short* __restrict__ Vg,   // [B,12,T,64] bf16
    const float* __restrict__ b1, const float* __restrict__ w2,
    const float* __restrict__ b2, const float* __restrict__ w3,
    const float* __restrict__ b3, const float* __restrict__ w4,
    const float* __restrict__ b4,
    float* __restrict__ out)        // [B,T,768] fp32, pre-zeroed
{
    __shared__ short Ks[256 * 72];   // [o*32+t][72]  (64d used)
    __shared__ short Vt[2624];       // transposed V: [d][t], group-padded
    __shared__ short As[2624];       // A weights:    [l][t], group-padded

    const int blk = blockIdx.x;          // ((b*12+h)*8+lt)*4 + qtr
    const int qtr = blk & 3;
    const int lt  = (blk >> 2) & 7;
    const int bh  = blk >> 5;
    const int h   = bh % NH;
    const int b   = bh / NH;
    const int l0  = lt * 64;
    const int tb  = qtr * 128;

    const int tid  = threadIdx.x;
    const int wv   = tid >> 6;
    const int lane = tid & 63;
    const int col  = lane & 15;
    const int quad = lane >> 4;
    const int wl   = wv >> 1;   // l-half for S'
    const int wt   = wv & 1;    // t-half for S'

    float b1r[8], w2r[8], w3r[4], b3r[4], w4r[4];
    #pragma unroll
    for (int o = 0; o < 8; o++) { b1r[o] = b1[h*8+o]; w2r[o] = w2[h*8+o]; }
    #pragma unroll
    for (int j = 0; j < 4; j++) { w3r[j] = w3[h*4+j]; b3r[j] = b3[h*4+j]; w4r[j] = w4[h*4+j]; }
    const float b2r = b2[h];
    const float b4r = b4[h];

    bf16x8 qa[2][2];
    {
        const short* qb = Qg + ((size_t)bh * TSEQ + l0 + wl*32 + col) * HD;
        qa[0][0] = *(const bf16x8*)&qb[quad*8];
        qa[0][1] = *(const bf16x8*)&qb[32 + quad*8];
        qa[1][0] = *(const bf16x8*)&qb[16*HD + quad*8];
        qa[1][1] = *(const bf16x8*)&qb[16*HD + 32 + quad*8];
    }

    floatx4 accO[4];
    #pragma unroll
    for (int d16 = 0; d16 < 4; d16++) accO[d16] = (floatx4){0.f, 0.f, 0.f, 0.f};

    const short* kbase = Kg + (size_t)bh * 8 * TSEQ * HD;
    const short* vbase = Vg + (size_t)bh * TSEQ * HD;

    const int tl = tid >> 3;   // 0..31 staging row
    const int dc = tid & 7;    // staging 16B chunk

    #pragma unroll 1
    for (int it = 0; it < 4; it++) {
        const int t0 = tb + it * 32;

        // loads issue here, overlapping the tail of the previous compute
        bf16x8 ktmp[8];
        #pragma unroll
        for (int o = 0; o < 8; o++)
            ktmp[o] = *(const bf16x8*)&kbase[((size_t)o * TSEQ + t0 + tl) * HD + dc*8];
        bf16x8 vtmp = *(const bf16x8*)&vbase[(size_t)(t0 + tl) * HD + dc*8];

        __syncthreads();

        #pragma unroll
        for (int o = 0; o < 8; o++)
            *(bf16x8*)&Ks[(o*32 + tl)*72 + dc*8] = ktmp[o];
        #pragma unroll
        for (int j = 0; j < 8; j++)
            Vt[vrow(dc*8 + j) + tl] = vtmp[j];   // transpose: Vt[d][t]

        __syncthreads();

        // --- S' (QK'^T) + talking-heads MLP (packed float2) ---
        floatx2 z2v[4];   // [li*2 + rpair], rpair 0 -> r{0,1}, 1 -> r{2,3}
        #pragma unroll
        for (int i_ = 0; i_ < 4; ++i_) z2v[i_] = (floatx2)(b2r);

        #pragma unroll
        for (int oh = 0; oh < 2; ++oh) {
            floatx4 accS[4][2];
            #pragma unroll
            for (int o4 = 0; o4 < 4; ++o4) {
                accS[o4][0] = (floatx4){0.f, 0.f, 0.f, 0.f};
                accS[o4][1] = (floatx4){0.f, 0.f, 0.f, 0.f};
            }
            #pragma unroll
            for (int k32 = 0; k32 < 2; ++k32) {
                #pragma unroll
                for (int o4 = 0; o4 < 4; ++o4) {
                    const int o_ = oh*4 + o4;
                    bf16x8 bfr = *(const bf16x8*)&Ks[(o_*32 + wt*16 + col)*72 + k32*32 + quad*8];
                    accS[o4][0] = __builtin_amdgcn_mfma_f32_16x16x32_bf16(qa[0][k32], bfr, accS[o4][0], 0, 0, 0);
                    accS[o4][1] = __builtin_amdgcn_mfma_f32_16x16x32_bf16(qa[1][k32], bfr, accS[o4][1], 0, 0, 0);
                }
            }
            #pragma unroll
            for (int li = 0; li < 2; ++li) {
                #pragma unroll
                for (int rp = 0; rp < 2; ++rp) {
                    #pragma unroll
                    for (int o4 = 0; o4 < 4; ++o4) {
                        floatx2 s;
                        s[0] = accS[o4][li][rp*2];
                        s[1] = accS[o4][li][rp*2 + 1];
                        floatx2 z1 = __builtin_elementwise_max(
                            s + (floatx2)(b1r[oh*4+o4]), (floatx2)(0.0f));
                        z2v[li*2+rp] = __builtin_elementwise_fma(
                            z1, (floatx2)(w2r[oh*4+o4]), z2v[li*2+rp]);
                    }
                }
            }
        }
        #pragma unroll
        for (int li = 0; li < 2; ++li) {
            #pragma unroll
            for (int rp = 0; rp < 2; ++rp) {
                floatx2 z2 = z2v[li*2+rp];
                floatx2 av = (floatx2)(b4r);
                #pragma unroll
                for (int j_ = 0; j_ < 4; ++j_) {
                    floatx2 z3 = __builtin_elementwise_max(
                        __builtin_elementwise_fma(z2, (floatx2)(w3r[j_]), (floatx2)(b3r[j_])),
                        (floatx2)(0.0f));
                    av = __builtin_elementwise_fma(z3, (floatx2)(w4r[j_]), av);
                }
                As[vrow(wl*32 + li*16 + quad*4 + rp*2)     + wt*16 + col] = f2bf(av[0]);
                As[vrow(wl*32 + li*16 + quad*4 + rp*2 + 1) + wt*16 + col] = f2bf(av[1]);
            }
        }
        __syncthreads();

        // --- PV ---
        bf16x8 afr = *(const bf16x8*)&As[vrow(wv*16 + col) + quad*8];
        #pragma unroll
        for (int d16 = 0; d16 < 4; ++d16) {
            bf16x8 vfr = *(const bf16x8*)&Vt[vrow(d16*16 + col) + quad*8];
            accO[d16] = __builtin_amdgcn_mfma_f32_16x16x32_bf16(afr, vfr, accO[d16], 0, 0, 0);
        }
    }

    // epilogue: hw fp32 fadd into out (4 t-quarter blocks accumulate)
    float* ob = out + ((size_t)(b*TSEQ + l0)) * E + h*64;
    #pragma unroll
    for (int d16 = 0; d16 < 4; d16++)
        #pragma unroll
        for (int r = 0; r < 4; r++)
            unsafeAtomicAdd(&ob[(size_t)(wv*16 + quad*4 + r) * E + d16*16 + col],
                            accO[d16][r]);
}

// ---------------------------------------------------------------------------
extern "C" void kernel_launch(void* const* d_in, const int* in_sizes, int n_in,
                              void* d_out, int out_size, void* d_ws, size_t ws_size,
                              hipStream_t stream) {
    const float* x  = (const float*)d_in[0];
    const float* wq = (const float*)d_in[1];
    const float* bq = (const float*)d_in[2];
    const float* wk = (const float*)d_in[3];
    const float* bk = (const float*)d_in[4];
    const float* wv = (const float*)d_in[5];
    const float* bv = (const float*)d_in[6];
    const float* w1 = (const float*)d_in[7];
    const float* b1 = (const float*)d_in[8];
    const float* w2 = (const float*)d_in[9];
    const float* b2 = (const float*)d_in[10];
    const float* w3 = (const float*)d_in[11];
    const float* b3 = (const float*)d_in[12];
    const float* w4 = (const float*)d_in[13];
    const float* b4 = (const float*)d_in[14];
    float* out = (float*)d_out;

    short* Qb = (short*)d_ws;                       // 786432 bf16
    short* Kb = Qb + 786432;                        // 786432 bf16
    short* Vb = Kb + 786432;                        // 786432 bf16
    short* Kp = Vb + 786432;                        // 6291456 bf16

    qkv_mfma<<<dim3(16, 12, 3), 256, 0, stream>>>(x, wq, bq, wk, bk, wv, bv, Qb, Kb, Vb);
    kmix_kernel<<<768, 256, 0, stream>>>(Kb, w1, Kp);
    attn_mfma<<<768, 256, 0, stream>>>(Qb, Kp, Vb, b1, w2, b2, w3, b3, w4, b4, out);
}

// Round 9
// 131.532 us; speedup vs baseline: 1.0425x; 1.0119x over previous
//
#include <hip/hip_runtime.h>

#define DEVINL __device__ __forceinline__

constexpr int E    = 768;
constexpr int TSEQ = 512;
constexpr int NH   = 12;
constexpr int HD   = 64;
constexpr float RSCALE = 0.036084391824351615f; // 1/sqrt(768)

typedef short bf16x8 __attribute__((ext_vector_type(8)));
typedef float floatx4 __attribute__((ext_vector_type(4)));
typedef float floatx2 __attribute__((ext_vector_type(2)));

DEVINL short f2bf(float x) {
    union { float f; unsigned u; } v; v.f = x;
    unsigned r = v.u + 0x7FFFu + ((v.u >> 16) & 1u);
    return (short)(r >> 16);
}
DEVINL float bf2f(short s) {
    union { unsigned u; float f; } v;
    v.u = ((unsigned)(unsigned short)s) << 16;
    return v.f;
}

// ---------------------------------------------------------------------------
// Kernel 0: fp32 -> bf16 conversion for x, wq, wk, wv (one pass).
// REINSTATED: x/W strips are re-read 12-16x by qkv tiles; bf16 halves that
// traffic — measured net win vs fused-fp32 reads (baseline 130.3 vs R7 133.3).
// ---------------------------------------------------------------------------
__global__ __launch_bounds__(256) void convert_kernel(
    const float* __restrict__ x,  const float* __restrict__ wq,
    const float* __restrict__ wk, const float* __restrict__ wv,
    short* __restrict__ xb, short* __restrict__ wqb,
    short* __restrict__ wkb, short* __restrict__ wvb)
{
    const int g = blockIdx.x * 256 + threadIdx.x;    // 319488 threads total
    const float* src; short* dst; int off;
    if (g < 98304)       { src = x;  dst = xb;  off = g * 8; }
    else if (g < 172032) { src = wq; dst = wqb; off = (g - 98304) * 8; }
    else if (g < 245760) { src = wk; dst = wkb; off = (g - 172032) * 8; }
    else                 { src = wv; dst = wvb; off = (g - 245760) * 8; }
    float4 f0 = *(const float4*)&src[off];
    float4 f1 = *(const float4*)&src[off + 4];
    bf16x8 o;
    o[0] = f2bf(f0.x); o[1] = f2bf(f0.y); o[2] = f2bf(f0.z); o[3] = f2bf(f0.w);
    o[4] = f2bf(f1.x); o[5] = f2bf(f1.y); o[6] = f2bf(f1.z); o[7] = f2bf(f1.w);
    *(bf16x8*)&dst[off] = o;
}

// ---------------------------------------------------------------------------
// Kernel 1: QKV projections via MFMA, bf16 inputs, register-prefetched
// staging. Block = 64x64 output tile, 4 waves. LDS rows padded to 72 bf16.
// ---------------------------------------------------------------------------
__global__ __launch_bounds__(256) void qkv_mfma(
    const short* __restrict__ xb,
    const short* __restrict__ wqb, const float* __restrict__ bq,
    const short* __restrict__ wkb, const float* __restrict__ bk,
    const short* __restrict__ wvb, const float* __restrict__ bv,
    short* __restrict__ Qo, short* __restrict__ Ko, short* __restrict__ Vo)
{
    const short* W; const float* bias; short* outp;
    if (blockIdx.z == 0)      { W = wqb; bias = bq; outp = Qo; }
    else if (blockIdx.z == 1) { W = wkb; bias = bk; outp = Ko; }
    else                      { W = wvb; bias = bv; outp = Vo; }

    __shared__ short As[64 * 72];
    __shared__ short Bs[64 * 72];

    const int m0   = blockIdx.x * 64;
    const int n0   = blockIdx.y * 64;    // == head * 64
    const int tid  = threadIdx.x;
    const int wvi  = tid >> 6;
    const int lane = tid & 63;
    const int col  = lane & 15;
    const int quad = lane >> 4;

    const int r0 = tid >> 3, kc0 = tid & 7;
    const int r1 = r0 + 32;

    floatx4 acc[4];
    #pragma unroll
    for (int i = 0; i < 4; i++) acc[i] = (floatx4){0.f, 0.f, 0.f, 0.f};

    bf16x8 st[2][4];   // [buf][a0,a1,b0,b1]

    #define QKV_LOAD(buf, kk) do { \
        st[buf][0] = *(const bf16x8*)&xb[(size_t)(m0 + r0) * E + (kk) + kc0*8]; \
        st[buf][1] = *(const bf16x8*)&xb[(size_t)(m0 + r1) * E + (kk) + kc0*8]; \
        st[buf][2] = *(const bf16x8*)&W [(size_t)(n0 + r0) * E + (kk) + kc0*8]; \
        st[buf][3] = *(const bf16x8*)&W [(size_t)(n0 + r1) * E + (kk) + kc0*8]; \
    } while (0)

    #define QKV_STAGE(buf) do { \
        *(bf16x8*)&As[r0*72 + kc0*8] = st[buf][0]; \
        *(bf16x8*)&As[r1*72 + kc0*8] = st[buf][1]; \
        *(bf16x8*)&Bs[r0*72 + kc0*8] = st[buf][2]; \
        *(bf16x8*)&Bs[r1*72 + kc0*8] = st[buf][3]; \
    } while (0)

    #define QKV_COMPUTE() do { \
        _Pragma("unroll") \
        for (int k32 = 0; k32 < 2; ++k32) { \
            bf16x8 bfr = *(const bf16x8*)&Bs[(wvi*16 + col)*72 + k32*32 + quad*8]; \
            _Pragma("unroll") \
            for (int ms = 0; ms < 4; ++ms) { \
                bf16x8 afr = *(const bf16x8*)&As[(ms*16 + col)*72 + k32*32 + quad*8]; \
                acc[ms] = __builtin_amdgcn_mfma_f32_16x16x32_bf16(afr, bfr, acc[ms], 0, 0, 0); \
            } \
        } \
    } while (0)

    QKV_LOAD(0, 0);
    #pragma unroll 1
    for (int it2 = 0; it2 < 6; ++it2) {
        const int k0 = it2 * 128;
        __syncthreads();
        QKV_STAGE(0);
        QKV_LOAD(1, k0 + 64);          // prefetch next tile during compute
        __syncthreads();
        QKV_COMPUTE();
        __syncthreads();
        QKV_STAGE(1);
        if (it2 < 5) QKV_LOAD(0, k0 + 128);
        __syncthreads();
        QKV_COMPUTE();
    }
    #undef QKV_LOAD
    #undef QKV_STAGE
    #undef QKV_COMPUTE

    const float bn = bias[n0 + wvi*16 + col];
    const int h = blockIdx.y;
    #pragma unroll
    for (int ms = 0; ms < 4; ms++) {
        #pragma unroll
        for (int r = 0; r < 4; r++) {
            int m = m0 + ms*16 + quad*4 + r;
            int bb = m >> 9, l = m & 511;
            outp[(((size_t)(bb*NH + h)) * TSEQ + l) * HD + wvi*16 + col] =
                f2bf(acc[ms][r] + bn);
        }
    }
}

// ---------------------------------------------------------------------------
// Kernel 2: Kp[b][h][o][t][d] = (1/scale) * sum_i w1[(h*8+o)*12+i] * K[b][i][t][d]
// 4 'o' outputs per thread -> 768 blocks / 3 waves per SIMD, 4x read dedup.
// ---------------------------------------------------------------------------
__global__ __launch_bounds__(256) void kmix_kernel(
    const short* __restrict__ K,   // [B,12,T,64] bf16
    const float* __restrict__ w1,  // [96,12] fp32
    short* __restrict__ Kp)        // [B,12,8,T,64] bf16
{
    const int g  = blockIdx.x * 256 + threadIdx.x;   // 196608 threads
    const int d8 = g & 7;
    const int t  = (g >> 3) & 511;
    const int o2 = (g >> 12) & 1;    // which group of 4 'o'
    const int bh = g >> 13;          // b*12 + h
    const int h  = bh % NH;
    const int b  = bh / NH;

    float kv[12][8];
    #pragma unroll
    for (int i = 0; i < 12; ++i) {
        bf16x8 raw = *(const bf16x8*)&K[(((size_t)(b*NH + i)) * TSEQ + t) * HD + d8*8];
        #pragma unroll
        for (int j = 0; j < 8; ++j) kv[i][j] = bf2f(raw[j]);
    }

    short* outbase = Kp + (((size_t)bh * 8) * TSEQ + t) * HD + d8*8;
    #pragma unroll
    for (int oo = 0; oo < 4; ++oo) {
        const int o = o2*4 + oo;
        float acc[8] = {};
        #pragma unroll
        for (int i = 0; i < 12; ++i) {
            const float w = w1[(h*8 + o)*12 + i] * RSCALE;
            #pragma unroll
            for (int j = 0; j < 8; ++j) acc[j] = fmaf(w, kv[i][j], acc[j]);
        }
        bf16x8 ov;
        #pragma unroll
        for (int j = 0; j < 8; ++j) ov[j] = f2bf(acc[j]);
        *(bf16x8*)&outbase[(size_t)o * TSEQ * HD] = ov;
    }
}

// group-of-8 padded row offset (conflict-free transpose writes + aligned b128 reads)
DEVINL int vrow(int r) { return r*40 + (r >> 3)*8; }

// ---------------------------------------------------------------------------
// Kernel 3: MFMA attention. Block = (b, h, l-tile 64, t-quarter 128).
// Single-buffered staging (no spill), pk-float2 MLP, atomic-fadd epilogue
// into pre-zeroed out (reduce kernel + P buffer eliminated).
// ---------------------------------------------------------------------------
__global__ __launch_bounds__(256, 3) void attn_mfma(
    const short* __restrict__ Qg,   // [B,12,T,64] bf16
    const short* __restrict__ Kg,   // [B,12,8,T,64] bf16
    const short* __restrict__ Vg,   // [B,12,T,64] bf16
    const float* __restrict__ b1, const float* __restrict__ w2,
    const float* __restrict__ b2, const float* __restrict__ w3,
    const float* __restrict__ b3, const float* __restrict__ w4,
    const float* __restrict__ b4,
    float* __restrict__ out)        // [B,T,768] fp32, pre-zeroed
{
    __shared__ short Ks[256 * 72];   // [o*32+t][72]  (64d used)
    __shared__ short Vt[2624];       // transposed V: [d][t], group-padded
    __shared__ short As[2624];       // A weights:    [l][t], group-padded

    const int blk = blockIdx.x;          // ((b*12+h)*8+lt)*4 + qtr
    const int qtr = blk & 3;
    const int lt  = (blk >> 2) & 7;
    const int bh  = blk >> 5;
    const int h   = bh % NH;
    const int b   = bh / NH;
    const int l0  = lt * 64;
    const int tb  = qtr * 128;

    const int tid  = threadIdx.x;
    const int wv   = tid >> 6;
    const int lane = tid & 63;
    const int col  = lane & 15;
    const int quad = lane >> 4;
    const int wl   = wv >> 1;   // l-half for S'
    const int wt   = wv & 1;    // t-half for S'

    float b1r[8], w2r[8], w3r[4], b3r[4], w4r[4];
    #pragma unroll
    for (int o = 0; o < 8; o++) { b1r[o] = b1[h*8+o]; w2r[o] = w2[h*8+o]; }
    #pragma unroll
    for (int j = 0; j < 4; j++) { w3r[j] = w3[h*4+j]; b3r[j] = b3[h*4+j]; w4r[j] = w4[h*4+j]; }
    const float b2r = b2[h];
    const float b4r = b4[h];

    bf16x8 qa[2][2];
    {
        const short* qb = Qg + ((size_t)bh * TSEQ + l0 + wl*32 + col) * HD;
        qa[0][0] = *(const bf16x8*)&qb[quad*8];
        qa[0][1] = *(const bf16x8*)&qb[32 + quad*8];
        qa[1][0] = *(const bf16x8*)&qb[16*HD + quad*8];
        qa[1][1] = *(const bf16x8*)&qb[16*HD + 32 + quad*8];
    }

    floatx4 accO[4];
    #pragma unroll
    for (int d16 = 0; d16 < 4; d16++) accO[d16] = (floatx4){0.f, 0.f, 0.f, 0.f};

    const short* kbase = Kg + (size_t)bh * 8 * TSEQ * HD;
    const short* vbase = Vg + (size_t)bh * TSEQ * HD;

    const int tl = tid >> 3;   // 0..31 staging row
    const int dc = tid & 7;    // staging 16B chunk

    #pragma unroll 1
    for (int it = 0; it < 4; it++) {
        const int t0 = tb + it * 32;

        // loads issue here, overlapping the tail of the previous compute
        bf16x8 ktmp[8];
        #pragma unroll
        for (int o = 0; o < 8; o++)
            ktmp[o] = *(const bf16x8*)&kbase[((size_t)o * TSEQ + t0 + tl) * HD + dc*8];
        bf16x8 vtmp = *(const bf16x8*)&vbase[(size_t)(t0 + tl) * HD + dc*8];

        __syncthreads();

        #pragma unroll
        for (int o = 0; o < 8; o++)
            *(bf16x8*)&Ks[(o*32 + tl)*72 + dc*8] = ktmp[o];
        #pragma unroll
        for (int j = 0; j < 8; j++)
            Vt[vrow(dc*8 + j) + tl] = vtmp[j];   // transpose: Vt[d][t]

        __syncthreads();

        // --- S' (QK'^T) + talking-heads MLP (packed float2) ---
        floatx2 z2v[4];   // [li*2 + rpair]
        #pragma unroll
        for (int i_ = 0; i_ < 4; ++i_) z2v[i_] = (floatx2)(b2r);

        #pragma unroll
        for (int oh = 0; oh < 2; ++oh) {
            floatx4 accS[4][2];
            #pragma unroll
            for (int o4 = 0; o4 < 4; ++o4) {
                accS[o4][0] = (floatx4){0.f, 0.f, 0.f, 0.f};
                accS[o4][1] = (floatx4){0.f, 0.f, 0.f, 0.f};
            }
            #pragma unroll
            for (int k32 = 0; k32 < 2; ++k32) {
                #pragma unroll
                for (int o4 = 0; o4 < 4; ++o4) {
                    const int o_ = oh*4 + o4;
                    bf16x8 bfr = *(const bf16x8*)&Ks[(o_*32 + wt*16 + col)*72 + k32*32 + quad*8];
                    accS[o4][0] = __builtin_amdgcn_mfma_f32_16x16x32_bf16(qa[0][k32], bfr, accS[o4][0], 0, 0, 0);
                    accS[o4][1] = __builtin_amdgcn_mfma_f32_16x16x32_bf16(qa[1][k32], bfr, accS[o4][1], 0, 0, 0);
                }
            }
            #pragma unroll
            for (int li = 0; li < 2; ++li) {
                #pragma unroll
                for (int rp = 0; rp < 2; ++rp) {
                    #pragma unroll
                    for (int o4 = 0; o4 < 4; ++o4) {
                        floatx2 s;
                        s[0] = accS[o4][li][rp*2];
                        s[1] = accS[o4][li][rp*2 + 1];
                        floatx2 z1 = __builtin_elementwise_max(
                            s + (floatx2)(b1r[oh*4+o4]), (floatx2)(0.0f));
                        z2v[li*2+rp] = __builtin_elementwise_fma(
                            z1, (floatx2)(w2r[oh*4+o4]), z2v[li*2+rp]);
                    }
                }
            }
        }
        #pragma unroll
        for (int li = 0; li < 2; ++li) {
            #pragma unroll
            for (int rp = 0; rp < 2; ++rp) {
                floatx2 z2 = z2v[li*2+rp];
                floatx2 av = (floatx2)(b4r);
                #pragma unroll
                for (int j_ = 0; j_ < 4; ++j_) {
                    floatx2 z3 = __builtin_elementwise_max(
                        __builtin_elementwise_fma(z2, (floatx2)(w3r[j_]), (floatx2)(b3r[j_])),
                        (floatx2)(0.0f));
                    av = __builtin_elementwise_fma(z3, (floatx2)(w4r[j_]), av);
                }
                As[vrow(wl*32 + li*16 + quad*4 + rp*2)     + wt*16 + col] = f2bf(av[0]);
                As[vrow(wl*32 + li*16 + quad*4 + rp*2 + 1) + wt*16 + col] = f2bf(av[1]);
            }
        }
        __syncthreads();

        // --- PV ---
        bf16x8 afr = *(const bf16x8*)&As[vrow(wv*16 + col) + quad*8];
        #pragma unroll
        for (int d16 = 0; d16 < 4; ++d16) {
            bf16x8 vfr = *(const bf16x8*)&Vt[vrow(d16*16 + col) + quad*8];
            accO[d16] = __builtin_amdgcn_mfma_f32_16x16x32_bf16(afr, vfr, accO[d16], 0, 0, 0);
        }
    }

    // epilogue: hw fp32 fadd into out (4 t-quarter blocks accumulate)
    float* ob = out + ((size_t)(b*TSEQ + l0)) * E + h*64;
    #pragma unroll
    for (int d16 = 0; d16 < 4; d16++)
        #pragma unroll
        for (int r = 0; r < 4; r++)
            unsafeAtomicAdd(&ob[(size_t)(wv*16 + quad*4 + r) * E + d16*16 + col],
                            accO[d16][r]);
}

// ---------------------------------------------------------------------------
extern "C" void kernel_launch(void* const* d_in, const int* in_sizes, int n_in,
                              void* d_out, int out_size, void* d_ws, size_t ws_size,
                              hipStream_t stream) {
    const float* x  = (const float*)d_in[0];
    const float* wq = (const float*)d_in[1];
    const float* bq = (const float*)d_in[2];
    const float* wk = (const float*)d_in[3];
    const float* bk = (const float*)d_in[4];
    const float* wv = (const float*)d_in[5];
    const float* bv = (const float*)d_in[6];
    const float* w1 = (const float*)d_in[7];
    const float* b1 = (const float*)d_in[8];
    const float* w2 = (const float*)d_in[9];
    const float* b2 = (const float*)d_in[10];
    const float* w3 = (const float*)d_in[11];
    const float* b3 = (const float*)d_in[12];
    const float* w4 = (const float*)d_in[13];
    const float* b4 = (const float*)d_in[14];
    float* out = (float*)d_out;

    short* Qb  = (short*)d_ws;                      // 786432 bf16
    short* Kb  = Qb + 786432;                       // 786432 bf16
    short* Vb  = Kb + 786432;                       // 786432 bf16
    short* Kp  = Vb + 786432;                       // 6291456 bf16
    short* xb  = Kp + 6291456;                      // 786432 bf16
    short* wqb = xb + 786432;                       // 589824 bf16
    short* wkb = wqb + 589824;
    short* wvb = wkb + 589824;

    convert_kernel<<<1248, 256, 0, stream>>>(x, wq, wk, wv, xb, wqb, wkb, wvb);
    qkv_mfma<<<dim3(16, 12, 3), 256, 0, stream>>>(xb, wqb, bq, wkb, bk, wvb, bv, Qb, Kb, Vb);
    kmix_kernel<<<768, 256, 0, stream>>>(Kb, w1, Kp);
    attn_mfma<<<768, 256, 0, stream>>>(Qb, Kp, Vb, b1, w2, b2, w3, b3, w4, b4, out);
}